// Round 18
// baseline (518.170 us; speedup 1.0000x reference)
//
#include <hip/hip_runtime.h>
#include <hip/hip_bf16.h>
#include <math.h>

// y[M,N] = x[M,K] . W[N,K]^T,  W = q*s + z,  G=128, K=4096
// Pure-i8 path (validated R15-R17, absmax 0.469 vs thr 1.045):
//   wq[n,k] = round(q*s_g / swn),  swn = 15*max_g s[g,n]/127   (int8)
//   xq[m,k] = per-row int8 quant of x (sx[m]);  XS[m,g] = true group sums
//   y = sx[m]*swn[n]*P + sum_g z[g,n]*XS[m,g],  P exact i32 (MFMA-only acc)
// R18: wave-parity de-phasing -- odd-parity waves traverse region-1 in a
// different order (QUAD(0,2) first) so co-SIMD waves' MFMA and DS windows
// overlap instead of lockstep. Same reads/MFMAs/epochs/registers/ledger.
// Fallbacks: bf16 two-pass m97 GEMM; fully-fused round-1 kernel.

typedef __bf16 bf16x8 __attribute__((ext_vector_type(8)));
typedef float  f32x4  __attribute__((ext_vector_type(4)));
typedef int    i32x4  __attribute__((ext_vector_type(4)));

#define GL(gsrc, ldst)                                                       \
    __builtin_amdgcn_global_load_lds(                                        \
        (__attribute__((address_space(1))) void*)(gsrc),                     \
        (__attribute__((address_space(3))) void*)(ldst), 16, 0, 0)

// ---------------- prep_all: wave wid<N -> W row; else X row ----------------
__global__ void prep_all(const float* __restrict__ X, const int* __restrict__ Q,
                         const float* __restrict__ S, const float* __restrict__ Z,
                         signed char* __restrict__ Xq, signed char* __restrict__ Wq,
                         float* __restrict__ SX, float* __restrict__ SW,
                         __bf16* __restrict__ XS, __bf16* __restrict__ ZT,
                         int M, int N, int K)
{
    const int lane = threadIdx.x & 63;
    const int wid  = blockIdx.x * (blockDim.x >> 6) + (threadIdx.x >> 6);
    const int NG   = K / 128;           // 32

    if (wid < N) {
        // ---- W row n: requant q*s -> int8 (coalesced), SW, ZT ----
        const int n = wid;
        const float sv = (lane < NG) ? S[(size_t)lane * N + n] : 0.f;
        float smax = sv;
#pragma unroll
        for (int off = 32; off > 0; off >>= 1)
            smax = fmaxf(smax, __shfl_xor(smax, off));
        const float inv = (smax > 0.f) ? 127.f / (15.f * smax) : 0.f;
        if (lane == 0) SW[n] = 15.f * smax / 127.f;
        if (lane < NG) ZT[(size_t)n * NG + lane] = (__bf16)Z[(size_t)lane * N + n];
        const int4* qrow = (const int4*)(Q + (size_t)n * K);   // 16B/lane
        int*        wrow = (int*)(Wq + (size_t)n * K);         // 4B/lane
#pragma unroll
        for (int j = 0; j < 16; ++j) {
            const int4 a = qrow[j * 64 + lane];                // elems j*256+lane*4
            const int g = 2 * j + (lane >> 5);
            const float f = __shfl(sv, g) * inv;               // q*f <= 127
            int v0 = (int)rintf((float)a.x * f);
            int v1 = (int)rintf((float)a.y * f);
            int v2 = (int)rintf((float)a.z * f);
            int v3 = (int)rintf((float)a.w * f);
            v0 = v0 > 127 ? 127 : v0;  v1 = v1 > 127 ? 127 : v1;
            v2 = v2 > 127 ? 127 : v2;  v3 = v3 > 127 ? 127 : v3;
            wrow[j * 64 + lane] = (v0 & 0xff) | ((v1 & 0xff) << 8) |
                                  ((v2 & 0xff) << 16) | ((v3 & 0xff) << 24);
        }
    } else if (wid < N + M) {
        // ---- X row m: per-row int8 quant + sx + group sums ----
        const int m = wid - N;
        const float4* xr = (const float4*)(X + (size_t)m * K);
        float4 v[16];
        float gs[16];
        float amax = 0.f;
#pragma unroll
        for (int j = 0; j < 16; ++j) {
            v[j] = xr[lane + j * 64];
            gs[j] = v[j].x + v[j].y + v[j].z + v[j].w;
            amax = fmaxf(amax, fmaxf(fmaxf(fabsf(v[j].x), fabsf(v[j].y)),
                                     fmaxf(fabsf(v[j].z), fabsf(v[j].w))));
        }
#pragma unroll
        for (int off = 32; off > 0; off >>= 1)
            amax = fmaxf(amax, __shfl_xor(amax, off));
#pragma unroll
        for (int j = 0; j < 16; ++j) {
#pragma unroll
            for (int off = 16; off > 0; off >>= 1)
                gs[j] += __shfl_xor(gs[j], off);
        }
        if ((lane & 31) == 0) {
            const int hb = lane >> 5;
#pragma unroll
            for (int j = 0; j < 16; ++j)
                XS[(size_t)m * NG + 2 * j + hb] = (__bf16)gs[j];
        }
        const float inv = amax > 0.f ? 127.f / amax : 0.f;
        if (lane == 0) SX[m] = amax / 127.f;
        int* xq4 = (int*)(Xq + (size_t)m * K);
#pragma unroll
        for (int j = 0; j < 16; ++j) {
            int a = (int)rintf(v[j].x * inv);
            int b = (int)rintf(v[j].y * inv);
            int c = (int)rintf(v[j].z * inv);
            int d = (int)rintf(v[j].w * inv);
            a = a > 127 ? 127 : (a < -127 ? -127 : a);
            b = b > 127 ? 127 : (b < -127 ? -127 : b);
            c = c > 127 ? 127 : (c < -127 ? -127 : c);
            d = d > 127 ? 127 : (d < -127 ? -127 : d);
            xq4[lane + j * 64] = (a & 0xff) | ((b & 0xff) << 8) |
                                 ((c & 0xff) << 16) | ((d & 0xff) << 24);
        }
    }
}

// ---------------- i8 GEMM: pure int accumulate, parity-dephased ----------
#define PH_BAR  asm volatile("s_barrier" ::: "memory")
#define VMC(n)  asm volatile("s_waitcnt vmcnt(" #n ")" ::: "memory")

#define STAGE_A(BUF, H, T) do {                                               \
    GL(pa0 + (H) * hstep + (size_t)(T) * 128, sm + (BUF)*32768 + (H)*16384 + cb0); \
    GL(pa1 + (H) * hstep + (size_t)(T) * 128, sm + (BUF)*32768 + (H)*16384 + cb1); } while (0)
#define STAGE_B(BUF, H, T) do {                                               \
    GL(pb0 + (H) * hstep + (size_t)(T) * 128, sm + 65536 + (BUF)*32768 + (H)*16384 + cb0); \
    GL(pb1 + (H) * hstep + (size_t)(T) * 128, sm + 65536 + (BUF)*32768 + (H)*16384 + cb1); } while (0)

#define RDAI(RBASE, BUF)                                                      \
    _Pragma("unroll")                                                         \
    for (int mq = 0; mq < 4; ++mq) {                                          \
        const int r_ = (RBASE) + mq * 16 + lr;                                \
        const int rb_ = (BUF)*32768 + wm*16384 + r_*128;                      \
        const int sw_ = (r_ & 7) << 4;                                        \
        afi[mq][0] = *(const i32x4*)(sm + rb_ + ((lk*16) ^ sw_));             \
        afi[mq][1] = *(const i32x4*)(sm + rb_ + (((4+lk)*16) ^ sw_));         \
    }
#define RDBI(N0, N1, BUF)                                                     \
    _Pragma("unroll")                                                         \
    for (int nq = (N0); nq < (N1); ++nq) {                                    \
        const int r_ = (wn & 1) * 64 + nq * 16 + lr;                          \
        const int rb_ = 65536 + (BUF)*32768 + (wn>>1)*16384 + r_*128;         \
        const int sw_ = (r_ & 7) << 4;                                        \
        bqi[nq][0] = *(const i32x4*)(sm + rb_ + ((lk*16) ^ sw_));             \
        bqi[nq][1] = *(const i32x4*)(sm + rb_ + (((4+lk)*16) ^ sw_));         \
    }
#define QUADI(MLO, NLO) do {                                                  \
    __builtin_amdgcn_s_setprio(1);                                            \
    _Pragma("unroll")                                                         \
    for (int mq = 0; mq < 4; ++mq)                                            \
        _Pragma("unroll")                                                     \
        for (int nq = 0; nq < 2; ++nq) {                                      \
            acc[(MLO)+mq][(NLO)+nq] = __builtin_amdgcn_mfma_i32_16x16x64_i8(  \
                afi[mq][0], bqi[(NLO)+nq][0], acc[(MLO)+mq][(NLO)+nq], 0,0,0);\
            acc[(MLO)+mq][(NLO)+nq] = __builtin_amdgcn_mfma_i32_16x16x64_i8(  \
                afi[mq][1], bqi[(NLO)+nq][1], acc[(MLO)+mq][(NLO)+nq], 0,0,0);\
        }                                                                     \
    __builtin_amdgcn_s_setprio(0); } while (0)

// Region-1 in two orders (same reads/MFMAs/registers; only order differs).
// MODE 0: full staging + vmcnt(6); MODE 1: B-h1 stage only + vmcnt(0); MODE 2: bare.
#define TILEI(T, BUF, MODE) do {                                              \
    if (wodd) {                                                               \
        RDAI(0, BUF);                                                         \
        RDBI(2, 4, BUF);                                                      \
        if ((MODE) < 2) { STAGE_B((BUF)^1, 1, (T)+1); }                       \
        QUADI(0, 2);                                                          \
        RDBI(0, 2, BUF);                                                      \
        QUADI(0, 0);                                                          \
        RDAI(64, BUF);                                                        \
    } else {                                                                  \
        RDAI(0, BUF);                                                         \
        RDBI(0, 2, BUF);                                                      \
        if ((MODE) < 2) { STAGE_B((BUF)^1, 1, (T)+1); }                       \
        QUADI(0, 0);                                                          \
        RDBI(2, 4, BUF);                                                      \
        QUADI(0, 2);                                                          \
        RDAI(64, BUF);                                                        \
    }                                                                         \
    PH_BAR;                                                                   \
    QUADI(4, 2);                                                              \
    PH_BAR;                                                                   \
    if ((MODE) == 0) { STAGE_B(BUF, 0, (T)+2);                                \
                       STAGE_A(BUF, 0, (T)+2); STAGE_A(BUF, 1, (T)+2);        \
                       VMC(6); }                                              \
    else if ((MODE) == 1) { VMC(0); }                                         \
    PH_BAR;                                                                   \
    QUADI(4, 0);                                                              \
} while (0)

__global__ __launch_bounds__(512, 2)
void gemm_i8(const signed char* __restrict__ A, const signed char* __restrict__ B,
             const float* __restrict__ SW, const float* __restrict__ SX,
             const __bf16* __restrict__ XS, const __bf16* __restrict__ ZT,
             float* __restrict__ Y, int M, int N, int K)
{
    extern __shared__ __align__(16) char sm[];
    const int tid  = threadIdx.x;
    const int lane = tid & 63;
    const int w    = tid >> 6;
    const int wm   = w >> 2;
    const int wn   = w & 3;
    const int lr   = lane & 15;
    const int lk   = lane >> 4;
    // parity differs between co-SIMD waves under both common wave->SIMD
    // mappings (round-robin w%4 pairs {w,w+4}; consecutive pairs {2k,2k+1}).
    const bool wodd = ((w ^ (w >> 2)) & 1) != 0;
    const int nbn  = N / 256;
    const int nbm  = M / 256;
    const int nt   = K / 128;

    int bm, bn;
    if ((nbm & 3) == 0 && (nbn & 1) == 0) {
        const int xcd = blockIdx.x & 7;
        const int p   = blockIdx.x >> 3;
        const int rm  = nbm >> 2;
        const int rn  = nbn >> 1;
        bm = (xcd >> 1) * rm + p / rn;
        bn = (xcd & 1) * rn + p % rn;
    } else {
        bm = blockIdx.x / nbn;
        bn = blockIdx.x - bm * nbn;
    }

    const int ls    = (lane & 56) | ((lane ^ (lane >> 3)) & 7);
    const int rowA0 = w * 8 + (ls >> 3);
    const int rowA1 = 64 + w * 8 + (ls >> 3);
    const int colg  = (ls & 7) * 16;
    const signed char* pa0 = A + (size_t)(bm * 256 + rowA0) * K + colg;
    const signed char* pa1 = A + (size_t)(bm * 256 + rowA1) * K + colg;
    const signed char* pb0 = B + (size_t)(bn * 256 + rowA0) * K + colg;
    const signed char* pb1 = B + (size_t)(bn * 256 + rowA1) * K + colg;
    const size_t hstep = (size_t)128 * K;
    const int cb0 = w * 1024;
    const int cb1 = (8 + w) * 1024;

    i32x4 acc[8][4] = {};
    i32x4 afi[4][2];
    i32x4 bqi[4][2];

    STAGE_A(0, 0, 0); STAGE_A(0, 1, 0); STAGE_B(0, 0, 0); STAGE_B(0, 1, 0);
    STAGE_B(1, 0, 1); STAGE_A(1, 0, 1); STAGE_A(1, 1, 1);
    VMC(6);
    PH_BAR;

    for (int t = 0; t + 3 < nt; t += 2) {
        TILEI(t,     0, 0);
        TILEI(t + 1, 1, 0);
    }
    TILEI(nt - 2, 0, 1);
    TILEI(nt - 1, 1, 2);

    // epilogue: out = P * sx[row]*sw[col] + z-term (K=32 bf16 MFMA, exact sums)
    const int rowb = bm * 256 + wm * 128;
    const int colb = bn * 256 + wn * 64;
    bf16x8 zbf[4];
    float swv[4];
#pragma unroll
    for (int nq = 0; nq < 4; ++nq) {
        zbf[nq] = *(const bf16x8*)(ZT + (size_t)(colb + nq * 16 + lr) * 32 + lk * 8);
        swv[nq] = SW[colb + nq * 16 + lr];
    }
#pragma unroll
    for (int mq = 0; mq < 8; ++mq) {
        const bf16x8 za = *(const bf16x8*)(XS + (size_t)(rowb + mq * 16 + lr) * 32 + lk * 8);
        float sxv[4];
#pragma unroll
        for (int r = 0; r < 4; ++r)
            sxv[r] = SX[rowb + mq * 16 + lk * 4 + r];
#pragma unroll
        for (int nq = 0; nq < 4; ++nq) {
            f32x4 zacc = {0.f, 0.f, 0.f, 0.f};
            zacc = __builtin_amdgcn_mfma_f32_16x16x32_bf16(za, zbf[nq], zacc, 0, 0, 0);
            float* yp = Y + (size_t)(rowb + mq * 16 + lk * 4) * N + colb + nq * 16 + lr;
#pragma unroll
            for (int r = 0; r < 4; ++r)
                yp[(size_t)r * N] = (float)acc[mq][nq][r] * (sxv[r] * swv[nq]) + zacc[r];
        }
    }
}

// ---------------- bf16 fallback: prep + m97 GEMM ----------------
__global__ void prep_ab(const float* __restrict__ X, const int* __restrict__ Q,
                        const float* __restrict__ S, const float* __restrict__ Z,
                        __bf16* __restrict__ Xo, __bf16* __restrict__ Wo,
                        long n8x, int N, int K, int G)
{
    const int K8 = K >> 3;
    const long n8w = (long)N * K8;
    const long tot = n8x + n8w;
    long i = (long)blockIdx.x * blockDim.x + threadIdx.x;
    const long stride = (long)gridDim.x * blockDim.x;
    for (; i < tot; i += stride) {
        if (i < n8x) {
            const float4 v0 = ((const float4*)X)[i * 2];
            const float4 v1 = ((const float4*)X)[i * 2 + 1];
            bf16x8 u;
            u[0] = (__bf16)v0.x; u[1] = (__bf16)v0.y;
            u[2] = (__bf16)v0.z; u[3] = (__bf16)v0.w;
            u[4] = (__bf16)v1.x; u[5] = (__bf16)v1.y;
            u[6] = (__bf16)v1.z; u[7] = (__bf16)v1.w;
            ((bf16x8*)Xo)[i] = u;
        } else {
            const long j = i - n8x;
            const int n  = (int)(j / K8);
            const int kc = (int)(j - (long)n * K8);
            const int g  = (kc << 3) / G;
            const float s = S[(size_t)g * N + n];
            const float z = Z[(size_t)g * N + n];
            const int4 q0 = ((const int4*)Q)[j * 2];
            const int4 q1 = ((const int4*)Q)[j * 2 + 1];
            bf16x8 u;
            u[0] = (__bf16)((float)q0.x * s + z);
            u[1] = (__bf16)((float)q0.y * s + z);
            u[2] = (__bf16)((float)q0.z * s + z);
            u[3] = (__bf16)((float)q0.w * s + z);
            u[4] = (__bf16)((float)q1.x * s + z);
            u[5] = (__bf16)((float)q1.y * s + z);
            u[6] = (__bf16)((float)q1.z * s + z);
            u[7] = (__bf16)((float)q1.w * s + z);
            ((bf16x8*)Wo)[j] = u;
        }
    }
}

#define TM 128
#define TN 128
#define TK 64

__global__ __launch_bounds__(256)
void gemm_bf16_bt(const __bf16* __restrict__ A, const __bf16* __restrict__ B,
                  float* __restrict__ Y, int M, int N, int K)
{
    __shared__ __attribute__((aligned(16))) __bf16 Al[TM * TK];
    __shared__ __attribute__((aligned(16))) __bf16 Bl[TN * TK];

    const int tid  = threadIdx.x;
    const int lane = tid & 63;
    const int wv   = tid >> 6;
    const int nbn  = N / TN;
    const int bm   = blockIdx.x / nbn;
    const int bn   = blockIdx.x - bm * nbn;

    const __bf16* ga = A + ((size_t)(bm * TM + wv * 32 + (lane >> 3))) * K + (lane & 7) * 8;
    const __bf16* gb = B + ((size_t)(bn * TN + wv * 32 + (lane >> 3))) * K + (lane & 7) * 8;

    const int lr = lane & 15;
    const int lk = lane >> 4;
    const int wmm = (wv >> 1) * 64;
    const int wnn = (wv & 1) * 64;

    f32x4 acc[4][4] = {};
    const int ntile = K / TK;
    for (int t = 0; t < ntile; ++t) {
#pragma unroll
        for (int i = 0; i < 4; ++i)
            GL(ga + (size_t)i * 8 * K, &Al[(wv * 32 + i * 8) * TK]);
#pragma unroll
        for (int i = 0; i < 4; ++i)
            GL(gb + (size_t)i * 8 * K, &Bl[(wv * 32 + i * 8) * TK]);
        __syncthreads();
#pragma unroll
        for (int ks = 0; ks < 2; ++ks) {
            bf16x8 a2[4], b2[4];
#pragma unroll
            for (int i = 0; i < 4; ++i)
                a2[i] = *(const bf16x8*)&Al[(wmm + i * 16 + lr) * TK + ks * 32 + lk * 8];
#pragma unroll
            for (int j = 0; j < 4; ++j)
                b2[j] = *(const bf16x8*)&Bl[(wnn + j * 16 + lr) * TK + ks * 32 + lk * 8];
#pragma unroll
            for (int i = 0; i < 4; ++i)
#pragma unroll
                for (int j = 0; j < 4; ++j)
                    acc[i][j] = __builtin_amdgcn_mfma_f32_16x16x32_bf16(
                        a2[i], b2[j], acc[i][j], 0, 0, 0);
        }
        __syncthreads();
        ga += TK; gb += TK;
    }
    const int rowb = lk * 4;
#pragma unroll
    for (int i = 0; i < 4; ++i)
#pragma unroll
        for (int j = 0; j < 4; ++j) {
            const int col = bn * TN + wnn + j * 16 + lr;
            float* yp = Y + (size_t)(bm * TM + wmm + i * 16 + rowb) * N + col;
#pragma unroll
            for (int r = 0; r < 4; ++r)
                yp[(size_t)r * N] = acc[i][j][r];
        }
}

__global__ __launch_bounds__(256, 2)
void qlin_fused(const float* __restrict__ X, const int* __restrict__ Q,
                const float* __restrict__ S, const float* __restrict__ Z,
                float* __restrict__ Y, int M, int N, int K, int G)
{
    __shared__ __attribute__((aligned(16))) __bf16 Al[TM * TK];
    __shared__ __attribute__((aligned(16))) __bf16 Bl[TN * TK];

    const int tid = threadIdx.x;
    const int nbn = N / TN;
    const int bm = blockIdx.x / nbn;
    const int bn = blockIdx.x % nbn;

    const float* ap[4];
    const int*   qp[4];
    int nIdx[4], ldsOff[4];
#pragma unroll
    for (int i = 0; i < 4; ++i) {
        const int c   = tid + i * 256;
        const int row = c >> 3;
        const int c8  = c & 7;
        ldsOff[i] = row * TK + (c8 ^ (row & 7)) * 8;
        ap[i]   = X + (size_t)(bm * TM + row) * K + c8 * 8;
        qp[i]   = Q + (size_t)(bn * TN + row) * K + c8 * 8;
        nIdx[i] = bn * TN + row;
    }
    const int lane = tid & 63;
    const int wv   = tid >> 6;
    const int wmm  = (wv >> 1) * 64;
    const int wnn  = (wv & 1) * 64;
    const int lr   = lane & 15;
    const int lk   = lane >> 4;

    f32x4 acc[4][4] = {};
    const int ntile = K / TK;
    const int gstep = G / TK;
    int g = 0, gc = 0;
    for (int t = 0; t < ntile; ++t) {
#pragma unroll
        for (int i = 0; i < 4; ++i) {
            const float4 v0 = *(const float4*)(ap[i]);
            const float4 v1 = *(const float4*)(ap[i] + 4);
            bf16x8 u;
            u[0] = (__bf16)v0.x; u[1] = (__bf16)v0.y;
            u[2] = (__bf16)v0.z; u[3] = (__bf16)v0.w;
            u[4] = (__bf16)v1.x; u[5] = (__bf16)v1.y;
            u[6] = (__bf16)v1.z; u[7] = (__bf16)v1.w;
            *(bf16x8*)&Al[ldsOff[i]] = u;
            ap[i] += TK;
        }
#pragma unroll
        for (int i = 0; i < 4; ++i) {
            const int4 q0 = *(const int4*)(qp[i]);
            const int4 q1 = *(const int4*)(qp[i] + 4);
            const float s = S[(size_t)g * N + nIdx[i]];
            const float z = Z[(size_t)g * N + nIdx[i]];
            bf16x8 u;
            u[0] = (__bf16)((float)q0.x * s + z);
            u[1] = (__bf16)((float)q0.y * s + z);
            u[2] = (__bf16)((float)q0.z * s + z);
            u[3] = (__bf16)((float)q0.w * s + z);
            u[4] = (__bf16)((float)q1.x * s + z);
            u[5] = (__bf16)((float)q1.y * s + z);
            u[6] = (__bf16)((float)q1.z * s + z);
            u[7] = (__bf16)((float)q1.w * s + z);
            *(bf16x8*)&Bl[ldsOff[i]] = u;
            qp[i] += TK;
        }
        __syncthreads();
#pragma unroll
        for (int ks = 0; ks < 2; ++ks) {
            bf16x8 a2[4], b2[4];
#pragma unroll
            for (int i = 0; i < 4; ++i) {
                const int row = wmm + i * 16 + lr;
                a2[i] = *(const bf16x8*)&Al[row * TK + ((ks * 4 + lk) ^ (row & 7)) * 8];
            }
#pragma unroll
            for (int j = 0; j < 4; ++j) {
                const int row = wnn + j * 16 + lr;
                b2[j] = *(const bf16x8*)&Bl[row * TK + ((ks * 4 + lk) ^ (row & 7)) * 8];
            }
#pragma unroll
            for (int i = 0; i < 4; ++i)
#pragma unroll
                for (int j = 0; j < 4; ++j)
                    acc[i][j] = __builtin_amdgcn_mfma_f32_16x16x32_bf16(
                        a2[i], b2[j], acc[i][j], 0, 0, 0);
        }
        __syncthreads();
        if (++gc == gstep) { gc = 0; ++g; }
    }
    const int rowb = lk * 4;
#pragma unroll
    for (int i = 0; i < 4; ++i)
#pragma unroll
        for (int j = 0; j < 4; ++j) {
            const int col = bn * TN + wnn + j * 16 + lr;
            float* yp = Y + (size_t)(bm * TM + wmm + i * 16 + rowb) * N + col;
#pragma unroll
            for (int r = 0; r < 4; ++r)
                yp[(size_t)r * N] = acc[i][j][r];
        }
}

extern "C" void kernel_launch(void* const* d_in, const int* in_sizes, int n_in,
                              void* d_out, int out_size, void* d_ws, size_t ws_size,
                              hipStream_t stream)
{
    const float* X  = (const float*)d_in[0];
    const int*   Q  = (const int*)d_in[1];
    const float* S  = (const float*)d_in[2];
    const float* Z  = (const float*)d_in[3];
    float*       Y  = (float*)d_out;

    const long long MK = in_sizes[0];
    const long long NK = in_sizes[1];
    const long long GN = in_sizes[2];
    const int G = (int)(NK / GN);
    const long long kk = NK * MK / (long long)out_size;
    const int K = (int)llround(sqrt((double)kk));
    const int M = (int)(MK / K);
    const int N = (int)(NK / K);

    const size_t needI = (size_t)MK + (size_t)NK + 4ull * M + 64ull * M +
                         64ull * N + 4ull * N;
    bool i8ok = (G == 128) && (K == 4096) && (M % 256 == 0) && (N % 256 == 0) &&
                (ws_size >= needI);
    if (i8ok) {
        if (hipFuncSetAttribute((const void*)gemm_i8,
                                hipFuncAttributeMaxDynamicSharedMemorySize,
                                131072) != hipSuccess)
            i8ok = false;
        (void)hipGetLastError();
    }
    if (i8ok) {
        signed char* Xq = (signed char*)d_ws;
        signed char* Wq = Xq + MK;
        float*       SX = (float*)(Wq + NK);
        __bf16*      XS = (__bf16*)((char*)SX + 4ull * M);
        __bf16*      ZT = (__bf16*)((char*)XS + 64ull * M);
        float*       SW = (float*)((char*)ZT + 64ull * N);

        const int nwaves = N + M;
        const int nblk   = (nwaves + 3) / 4;          // 4 waves per 256-thr block
        prep_all<<<nblk, 256, 0, stream>>>(X, Q, S, Z, Xq, Wq, SX, SW, XS, ZT,
                                           M, N, K);
        gemm_i8<<<(M / 256) * (N / 256), 512, 131072, stream>>>(
            Xq, Wq, SW, SX, XS, ZT, Y, M, N, K);
        if (hipGetLastError() == hipSuccess) return;
    }

    const size_t need = ((size_t)M * K + (size_t)N * K) * sizeof(__bf16);
    if (ws_size >= need) {
        __bf16* Xbf = (__bf16*)d_ws;
        __bf16* Wbf = Xbf + (size_t)M * K;
        prep_ab<<<2048, 256, 0, stream>>>(X, Q, S, Z, Xbf, Wbf,
                                          (long)M * K / 8, N, K, G);
        gemm_bf16_bt<<<(M / TM) * (N / TN), 256, 0, stream>>>(Xbf, Wbf, Y, M, N, K);
    } else {
        qlin_fused<<<(M / TM) * (N / TN), 256, 0, stream>>>(X, Q, S, Z, Y, M, N, K, G);
    }
}

// Round 19
// 183.353 us; speedup vs baseline: 2.8261x; 2.8261x over previous
//
#include <hip/hip_runtime.h>
#include <hip/hip_bf16.h>
#include <math.h>

// y[M,N] = x[M,K] . W[N,K]^T,  W = q*s + z,  G=128, K=4096
// Pure-i8 path (validated R15-R17, absmax 0.469 vs thr 1.045):
//   wq[n,k] = round(q*s_g / swn),  swn = 15*max_g s[g,n]/127   (int8)
//   xq[m,k] = per-row int8 quant of x (sx[m]);  XS[m,g] = true group sums
//   y = sx[m]*swn[n]*P + sum_g z[g,n]*XS[m,g],  P exact i32 (MFMA-only acc)
// R19 = R17 verbatim (session best: 183.8 us). R18's parity-dephasing
// branch duplicated the inner loop -> register spill (WRITE 1.18 GB);
// reverted. This kernel's regalloc has zero slack -- do not perturb.
// Fallbacks: bf16 two-pass m97 GEMM; fully-fused round-1 kernel.

typedef __bf16 bf16x8 __attribute__((ext_vector_type(8)));
typedef float  f32x4  __attribute__((ext_vector_type(4)));
typedef int    i32x4  __attribute__((ext_vector_type(4)));

#define GL(gsrc, ldst)                                                       \
    __builtin_amdgcn_global_load_lds(                                        \
        (__attribute__((address_space(1))) void*)(gsrc),                     \
        (__attribute__((address_space(3))) void*)(ldst), 16, 0, 0)

// ---------------- prep_all: wave wid<N -> W row; else X row ----------------
__global__ void prep_all(const float* __restrict__ X, const int* __restrict__ Q,
                         const float* __restrict__ S, const float* __restrict__ Z,
                         signed char* __restrict__ Xq, signed char* __restrict__ Wq,
                         float* __restrict__ SX, float* __restrict__ SW,
                         __bf16* __restrict__ XS, __bf16* __restrict__ ZT,
                         int M, int N, int K)
{
    const int lane = threadIdx.x & 63;
    const int wid  = blockIdx.x * (blockDim.x >> 6) + (threadIdx.x >> 6);
    const int NG   = K / 128;           // 32

    if (wid < N) {
        // ---- W row n: requant q*s -> int8 (COALESCED), SW, ZT ----
        const int n = wid;
        const float sv = (lane < NG) ? S[(size_t)lane * N + n] : 0.f;
        float smax = sv;
#pragma unroll
        for (int off = 32; off > 0; off >>= 1)
            smax = fmaxf(smax, __shfl_xor(smax, off));
        const float inv = (smax > 0.f) ? 127.f / (15.f * smax) : 0.f;
        if (lane == 0) SW[n] = 15.f * smax / 127.f;
        if (lane < NG) ZT[(size_t)n * NG + lane] = (__bf16)Z[(size_t)lane * N + n];
        const int4* qrow = (const int4*)(Q + (size_t)n * K);   // 16B/lane
        int*        wrow = (int*)(Wq + (size_t)n * K);         // 4B/lane
#pragma unroll
        for (int j = 0; j < 16; ++j) {
            const int4 a = qrow[j * 64 + lane];                // elems j*256+lane*4
            const int g = 2 * j + (lane >> 5);
            const float f = __shfl(sv, g) * inv;               // q*f <= 127
            int v0 = (int)rintf((float)a.x * f);
            int v1 = (int)rintf((float)a.y * f);
            int v2 = (int)rintf((float)a.z * f);
            int v3 = (int)rintf((float)a.w * f);
            v0 = v0 > 127 ? 127 : v0;  v1 = v1 > 127 ? 127 : v1;
            v2 = v2 > 127 ? 127 : v2;  v3 = v3 > 127 ? 127 : v3;
            wrow[j * 64 + lane] = (v0 & 0xff) | ((v1 & 0xff) << 8) |
                                  ((v2 & 0xff) << 16) | ((v3 & 0xff) << 24);
        }
    } else if (wid < N + M) {
        // ---- X row m: per-row int8 quant + sx + group sums ----
        const int m = wid - N;
        const float4* xr = (const float4*)(X + (size_t)m * K);
        float4 v[16];
        float gs[16];
        float amax = 0.f;
#pragma unroll
        for (int j = 0; j < 16; ++j) {
            v[j] = xr[lane + j * 64];
            gs[j] = v[j].x + v[j].y + v[j].z + v[j].w;
            amax = fmaxf(amax, fmaxf(fmaxf(fabsf(v[j].x), fabsf(v[j].y)),
                                     fmaxf(fabsf(v[j].z), fabsf(v[j].w))));
        }
#pragma unroll
        for (int off = 32; off > 0; off >>= 1)
            amax = fmaxf(amax, __shfl_xor(amax, off));
#pragma unroll
        for (int j = 0; j < 16; ++j) {
#pragma unroll
            for (int off = 16; off > 0; off >>= 1)
                gs[j] += __shfl_xor(gs[j], off);
        }
        if ((lane & 31) == 0) {
            const int hb = lane >> 5;
#pragma unroll
            for (int j = 0; j < 16; ++j)
                XS[(size_t)m * NG + 2 * j + hb] = (__bf16)gs[j];
        }
        const float inv = amax > 0.f ? 127.f / amax : 0.f;
        if (lane == 0) SX[m] = amax / 127.f;
        int* xq4 = (int*)(Xq + (size_t)m * K);
#pragma unroll
        for (int j = 0; j < 16; ++j) {
            int a = (int)rintf(v[j].x * inv);
            int b = (int)rintf(v[j].y * inv);
            int c = (int)rintf(v[j].z * inv);
            int d = (int)rintf(v[j].w * inv);
            a = a > 127 ? 127 : (a < -127 ? -127 : a);
            b = b > 127 ? 127 : (b < -127 ? -127 : b);
            c = c > 127 ? 127 : (c < -127 ? -127 : c);
            d = d > 127 ? 127 : (d < -127 ? -127 : d);
            xq4[lane + j * 64] = (a & 0xff) | ((b & 0xff) << 8) |
                                 ((c & 0xff) << 16) | ((d & 0xff) << 24);
        }
    }
}

// ---------------- i8 GEMM: pure int accumulate, R12 schedule (R15) --------
#define PH_BAR  asm volatile("s_barrier" ::: "memory")
#define VMC(n)  asm volatile("s_waitcnt vmcnt(" #n ")" ::: "memory")

#define STAGE_A(BUF, H, T) do {                                               \
    GL(pa0 + (H) * hstep + (size_t)(T) * 128, sm + (BUF)*32768 + (H)*16384 + cb0); \
    GL(pa1 + (H) * hstep + (size_t)(T) * 128, sm + (BUF)*32768 + (H)*16384 + cb1); } while (0)
#define STAGE_B(BUF, H, T) do {                                               \
    GL(pb0 + (H) * hstep + (size_t)(T) * 128, sm + 65536 + (BUF)*32768 + (H)*16384 + cb0); \
    GL(pb1 + (H) * hstep + (size_t)(T) * 128, sm + 65536 + (BUF)*32768 + (H)*16384 + cb1); } while (0)

#define RDAI(RBASE, BUF)                                                      \
    _Pragma("unroll")                                                         \
    for (int mq = 0; mq < 4; ++mq) {                                          \
        const int r_ = (RBASE) + mq * 16 + lr;                                \
        const int rb_ = (BUF)*32768 + wm*16384 + r_*128;                      \
        const int sw_ = (r_ & 7) << 4;                                        \
        afi[mq][0] = *(const i32x4*)(sm + rb_ + ((lk*16) ^ sw_));             \
        afi[mq][1] = *(const i32x4*)(sm + rb_ + (((4+lk)*16) ^ sw_));         \
    }
#define RDBI(N0, N1, BUF)                                                     \
    _Pragma("unroll")                                                         \
    for (int nq = (N0); nq < (N1); ++nq) {                                    \
        const int r_ = (wn & 1) * 64 + nq * 16 + lr;                          \
        const int rb_ = 65536 + (BUF)*32768 + (wn>>1)*16384 + r_*128;         \
        const int sw_ = (r_ & 7) << 4;                                        \
        bqi[nq][0] = *(const i32x4*)(sm + rb_ + ((lk*16) ^ sw_));             \
        bqi[nq][1] = *(const i32x4*)(sm + rb_ + (((4+lk)*16) ^ sw_));         \
    }
#define QUADI(MLO, NLO) do {                                                  \
    __builtin_amdgcn_s_setprio(1);                                            \
    _Pragma("unroll")                                                         \
    for (int mq = 0; mq < 4; ++mq)                                            \
        _Pragma("unroll")                                                     \
        for (int nq = 0; nq < 2; ++nq) {                                      \
            acc[(MLO)+mq][(NLO)+nq] = __builtin_amdgcn_mfma_i32_16x16x64_i8(  \
                afi[mq][0], bqi[(NLO)+nq][0], acc[(MLO)+mq][(NLO)+nq], 0,0,0);\
            acc[(MLO)+mq][(NLO)+nq] = __builtin_amdgcn_mfma_i32_16x16x64_i8(  \
                afi[mq][1], bqi[(NLO)+nq][1], acc[(MLO)+mq][(NLO)+nq], 0,0,0);\
        }                                                                     \
    __builtin_amdgcn_s_setprio(0); } while (0)

// MODE 0: full staging + vmcnt(6); MODE 1: B-h1 stage only + vmcnt(0); MODE 2: bare.
#define TILEI(T, BUF, MODE) do {                                              \
    RDAI(0, BUF);                                                             \
    RDBI(0, 2, BUF);                                                          \
    if ((MODE) < 2) { STAGE_B((BUF)^1, 1, (T)+1); }                           \
    QUADI(0, 0);                                                              \
    RDBI(2, 4, BUF);                                                          \
    QUADI(0, 2);                                                              \
    RDAI(64, BUF);                                                            \
    PH_BAR;                                                                   \
    QUADI(4, 2);                                                              \
    PH_BAR;                                                                   \
    if ((MODE) == 0) { STAGE_B(BUF, 0, (T)+2);                                \
                       STAGE_A(BUF, 0, (T)+2); STAGE_A(BUF, 1, (T)+2);        \
                       VMC(6); }                                              \
    else if ((MODE) == 1) { VMC(0); }                                         \
    PH_BAR;                                                                   \
    QUADI(4, 0);                                                              \
} while (0)

__global__ __launch_bounds__(512, 2)
void gemm_i8(const signed char* __restrict__ A, const signed char* __restrict__ B,
             const float* __restrict__ SW, const float* __restrict__ SX,
             const __bf16* __restrict__ XS, const __bf16* __restrict__ ZT,
             float* __restrict__ Y, int M, int N, int K)
{
    extern __shared__ __align__(16) char sm[];
    const int tid  = threadIdx.x;
    const int lane = tid & 63;
    const int w    = tid >> 6;
    const int wm   = w >> 2;
    const int wn   = w & 3;
    const int lr   = lane & 15;
    const int lk   = lane >> 4;
    const int nbn  = N / 256;
    const int nbm  = M / 256;
    const int nt   = K / 128;

    int bm, bn;
    if ((nbm & 3) == 0 && (nbn & 1) == 0) {
        const int xcd = blockIdx.x & 7;
        const int p   = blockIdx.x >> 3;
        const int rm  = nbm >> 2;
        const int rn  = nbn >> 1;
        bm = (xcd >> 1) * rm + p / rn;
        bn = (xcd & 1) * rn + p % rn;
    } else {
        bm = blockIdx.x / nbn;
        bn = blockIdx.x - bm * nbn;
    }

    const int ls    = (lane & 56) | ((lane ^ (lane >> 3)) & 7);
    const int rowA0 = w * 8 + (ls >> 3);
    const int rowA1 = 64 + w * 8 + (ls >> 3);
    const int colg  = (ls & 7) * 16;
    const signed char* pa0 = A + (size_t)(bm * 256 + rowA0) * K + colg;
    const signed char* pa1 = A + (size_t)(bm * 256 + rowA1) * K + colg;
    const signed char* pb0 = B + (size_t)(bn * 256 + rowA0) * K + colg;
    const signed char* pb1 = B + (size_t)(bn * 256 + rowA1) * K + colg;
    const size_t hstep = (size_t)128 * K;
    const int cb0 = w * 1024;
    const int cb1 = (8 + w) * 1024;

    i32x4 acc[8][4] = {};
    i32x4 afi[4][2];
    i32x4 bqi[4][2];

    STAGE_A(0, 0, 0); STAGE_A(0, 1, 0); STAGE_B(0, 0, 0); STAGE_B(0, 1, 0);
    STAGE_B(1, 0, 1); STAGE_A(1, 0, 1); STAGE_A(1, 1, 1);
    VMC(6);
    PH_BAR;

    for (int t = 0; t + 3 < nt; t += 2) {
        TILEI(t,     0, 0);
        TILEI(t + 1, 1, 0);
    }
    TILEI(nt - 2, 0, 1);
    TILEI(nt - 1, 1, 2);

    // epilogue: out = P * sx[row]*sw[col] + z-term (K=32 bf16 MFMA, exact sums)
    const int rowb = bm * 256 + wm * 128;
    const int colb = bn * 256 + wn * 64;
    bf16x8 zbf[4];
    float swv[4];
#pragma unroll
    for (int nq = 0; nq < 4; ++nq) {
        zbf[nq] = *(const bf16x8*)(ZT + (size_t)(colb + nq * 16 + lr) * 32 + lk * 8);
        swv[nq] = SW[colb + nq * 16 + lr];
    }
#pragma unroll
    for (int mq = 0; mq < 8; ++mq) {
        const bf16x8 za = *(const bf16x8*)(XS + (size_t)(rowb + mq * 16 + lr) * 32 + lk * 8);
        float sxv[4];
#pragma unroll
        for (int r = 0; r < 4; ++r)
            sxv[r] = SX[rowb + mq * 16 + lk * 4 + r];
#pragma unroll
        for (int nq = 0; nq < 4; ++nq) {
            f32x4 zacc = {0.f, 0.f, 0.f, 0.f};
            zacc = __builtin_amdgcn_mfma_f32_16x16x32_bf16(za, zbf[nq], zacc, 0, 0, 0);
            float* yp = Y + (size_t)(rowb + mq * 16 + lk * 4) * N + colb + nq * 16 + lr;
#pragma unroll
            for (int r = 0; r < 4; ++r)
                yp[(size_t)r * N] = (float)acc[mq][nq][r] * (sxv[r] * swv[nq]) + zacc[r];
        }
    }
}

// ---------------- bf16 fallback: prep + m97 GEMM ----------------
__global__ void prep_ab(const float* __restrict__ X, const int* __restrict__ Q,
                        const float* __restrict__ S, const float* __restrict__ Z,
                        __bf16* __restrict__ Xo, __bf16* __restrict__ Wo,
                        long n8x, int N, int K, int G)
{
    const int K8 = K >> 3;
    const long n8w = (long)N * K8;
    const long tot = n8x + n8w;
    long i = (long)blockIdx.x * blockDim.x + threadIdx.x;
    const long stride = (long)gridDim.x * blockDim.x;
    for (; i < tot; i += stride) {
        if (i < n8x) {
            const float4 v0 = ((const float4*)X)[i * 2];
            const float4 v1 = ((const float4*)X)[i * 2 + 1];
            bf16x8 u;
            u[0] = (__bf16)v0.x; u[1] = (__bf16)v0.y;
            u[2] = (__bf16)v0.z; u[3] = (__bf16)v0.w;
            u[4] = (__bf16)v1.x; u[5] = (__bf16)v1.y;
            u[6] = (__bf16)v1.z; u[7] = (__bf16)v1.w;
            ((bf16x8*)Xo)[i] = u;
        } else {
            const long j = i - n8x;
            const int n  = (int)(j / K8);
            const int kc = (int)(j - (long)n * K8);
            const int g  = (kc << 3) / G;
            const float s = S[(size_t)g * N + n];
            const float z = Z[(size_t)g * N + n];
            const int4 q0 = ((const int4*)Q)[j * 2];
            const int4 q1 = ((const int4*)Q)[j * 2 + 1];
            bf16x8 u;
            u[0] = (__bf16)((float)q0.x * s + z);
            u[1] = (__bf16)((float)q0.y * s + z);
            u[2] = (__bf16)((float)q0.z * s + z);
            u[3] = (__bf16)((float)q0.w * s + z);
            u[4] = (__bf16)((float)q1.x * s + z);
            u[5] = (__bf16)((float)q1.y * s + z);
            u[6] = (__bf16)((float)q1.z * s + z);
            u[7] = (__bf16)((float)q1.w * s + z);
            ((bf16x8*)Wo)[j] = u;
        }
    }
}

#define TM 128
#define TN 128
#define TK 64

__global__ __launch_bounds__(256)
void gemm_bf16_bt(const __bf16* __restrict__ A, const __bf16* __restrict__ B,
                  float* __restrict__ Y, int M, int N, int K)
{
    __shared__ __attribute__((aligned(16))) __bf16 Al[TM * TK];
    __shared__ __attribute__((aligned(16))) __bf16 Bl[TN * TK];

    const int tid  = threadIdx.x;
    const int lane = tid & 63;
    const int wv   = tid >> 6;
    const int nbn  = N / TN;
    const int bm   = blockIdx.x / nbn;
    const int bn   = blockIdx.x - bm * nbn;

    const __bf16* ga = A + ((size_t)(bm * TM + wv * 32 + (lane >> 3))) * K + (lane & 7) * 8;
    const __bf16* gb = B + ((size_t)(bn * TN + wv * 32 + (lane >> 3))) * K + (lane & 7) * 8;

    const int lr = lane & 15;
    const int lk = lane >> 4;
    const int wmm = (wv >> 1) * 64;
    const int wnn = (wv & 1) * 64;

    f32x4 acc[4][4] = {};
    const int ntile = K / TK;
    for (int t = 0; t < ntile; ++t) {
#pragma unroll
        for (int i = 0; i < 4; ++i)
            GL(ga + (size_t)i * 8 * K, &Al[(wv * 32 + i * 8) * TK]);
#pragma unroll
        for (int i = 0; i < 4; ++i)
            GL(gb + (size_t)i * 8 * K, &Bl[(wv * 32 + i * 8) * TK]);
        __syncthreads();
#pragma unroll
        for (int ks = 0; ks < 2; ++ks) {
            bf16x8 a2[4], b2[4];
#pragma unroll
            for (int i = 0; i < 4; ++i)
                a2[i] = *(const bf16x8*)&Al[(wmm + i * 16 + lr) * TK + ks * 32 + lk * 8];
#pragma unroll
            for (int j = 0; j < 4; ++j)
                b2[j] = *(const bf16x8*)&Bl[(wnn + j * 16 + lr) * TK + ks * 32 + lk * 8];
#pragma unroll
            for (int i = 0; i < 4; ++i)
#pragma unroll
                for (int j = 0; j < 4; ++j)
                    acc[i][j] = __builtin_amdgcn_mfma_f32_16x16x32_bf16(
                        a2[i], b2[j], acc[i][j], 0, 0, 0);
        }
        __syncthreads();
        ga += TK; gb += TK;
    }
    const int rowb = lk * 4;
#pragma unroll
    for (int i = 0; i < 4; ++i)
#pragma unroll
        for (int j = 0; j < 4; ++j) {
            const int col = bn * TN + wnn + j * 16 + lr;
            float* yp = Y + (size_t)(bm * TM + wmm + i * 16 + rowb) * N + col;
#pragma unroll
            for (int r = 0; r < 4; ++r)
                yp[(size_t)r * N] = acc[i][j][r];
        }
}

__global__ __launch_bounds__(256, 2)
void qlin_fused(const float* __restrict__ X, const int* __restrict__ Q,
                const float* __restrict__ S, const float* __restrict__ Z,
                float* __restrict__ Y, int M, int N, int K, int G)
{
    __shared__ __attribute__((aligned(16))) __bf16 Al[TM * TK];
    __shared__ __attribute__((aligned(16))) __bf16 Bl[TN * TK];

    const int tid = threadIdx.x;
    const int nbn = N / TN;
    const int bm = blockIdx.x / nbn;
    const int bn = blockIdx.x % nbn;

    const float* ap[4];
    const int*   qp[4];
    int nIdx[4], ldsOff[4];
#pragma unroll
    for (int i = 0; i < 4; ++i) {
        const int c   = tid + i * 256;
        const int row = c >> 3;
        const int c8  = c & 7;
        ldsOff[i] = row * TK + (c8 ^ (row & 7)) * 8;
        ap[i]   = X + (size_t)(bm * TM + row) * K + c8 * 8;
        qp[i]   = Q + (size_t)(bn * TN + row) * K + c8 * 8;
        nIdx[i] = bn * TN + row;
    }
    const int lane = tid & 63;
    const int wv   = tid >> 6;
    const int wmm  = (wv >> 1) * 64;
    const int wnn  = (wv & 1) * 64;
    const int lr   = lane & 15;
    const int lk   = lane >> 4;

    f32x4 acc[4][4] = {};
    const int ntile = K / TK;
    const int gstep = G / TK;
    int g = 0, gc = 0;
    for (int t = 0; t < ntile; ++t) {
#pragma unroll
        for (int i = 0; i < 4; ++i) {
            const float4 v0 = *(const float4*)(ap[i]);
            const float4 v1 = *(const float4*)(ap[i] + 4);
            bf16x8 u;
            u[0] = (__bf16)v0.x; u[1] = (__bf16)v0.y;
            u[2] = (__bf16)v0.z; u[3] = (__bf16)v0.w;
            u[4] = (__bf16)v1.x; u[5] = (__bf16)v1.y;
            u[6] = (__bf16)v1.z; u[7] = (__bf16)v1.w;
            *(bf16x8*)&Al[ldsOff[i]] = u;
            ap[i] += TK;
        }
#pragma unroll
        for (int i = 0; i < 4; ++i) {
            const int4 q0 = *(const int4*)(qp[i]);
            const int4 q1 = *(const int4*)(qp[i] + 4);
            const float s = S[(size_t)g * N + nIdx[i]];
            const float z = Z[(size_t)g * N + nIdx[i]];
            bf16x8 u;
            u[0] = (__bf16)((float)q0.x * s + z);
            u[1] = (__bf16)((float)q0.y * s + z);
            u[2] = (__bf16)((float)q0.z * s + z);
            u[3] = (__bf16)((float)q0.w * s + z);
            u[4] = (__bf16)((float)q1.x * s + z);
            u[5] = (__bf16)((float)q1.y * s + z);
            u[6] = (__bf16)((float)q1.z * s + z);
            u[7] = (__bf16)((float)q1.w * s + z);
            *(bf16x8*)&Bl[ldsOff[i]] = u;
            qp[i] += TK;
        }
        __syncthreads();
#pragma unroll
        for (int ks = 0; ks < 2; ++ks) {
            bf16x8 a2[4], b2[4];
#pragma unroll
            for (int i = 0; i < 4; ++i) {
                const int row = wmm + i * 16 + lr;
                a2[i] = *(const bf16x8*)&Al[row * TK + ((ks * 4 + lk) ^ (row & 7)) * 8];
            }
#pragma unroll
            for (int j = 0; j < 4; ++j) {
                const int row = wnn + j * 16 + lr;
                b2[j] = *(const bf16x8*)&Bl[row * TK + ((ks * 4 + lk) ^ (row & 7)) * 8];
            }
#pragma unroll
            for (int i = 0; i < 4; ++i)
#pragma unroll
                for (int j = 0; j < 4; ++j)
                    acc[i][j] = __builtin_amdgcn_mfma_f32_16x16x32_bf16(
                        a2[i], b2[j], acc[i][j], 0, 0, 0);
        }
        __syncthreads();
        if (++gc == gstep) { gc = 0; ++g; }
    }
    const int rowb = lk * 4;
#pragma unroll
    for (int i = 0; i < 4; ++i)
#pragma unroll
        for (int j = 0; j < 4; ++j) {
            const int col = bn * TN + wnn + j * 16 + lr;
            float* yp = Y + (size_t)(bm * TM + wmm + i * 16 + rowb) * N + col;
#pragma unroll
            for (int r = 0; r < 4; ++r)
                yp[(size_t)r * N] = acc[i][j][r];
        }
}

extern "C" void kernel_launch(void* const* d_in, const int* in_sizes, int n_in,
                              void* d_out, int out_size, void* d_ws, size_t ws_size,
                              hipStream_t stream)
{
    const float* X  = (const float*)d_in[0];
    const int*   Q  = (const int*)d_in[1];
    const float* S  = (const float*)d_in[2];
    const float* Z  = (const float*)d_in[3];
    float*       Y  = (float*)d_out;

    const long long MK = in_sizes[0];
    const long long NK = in_sizes[1];
    const long long GN = in_sizes[2];
    const int G = (int)(NK / GN);
    const long long kk = NK * MK / (long long)out_size;
    const int K = (int)llround(sqrt((double)kk));
    const int M = (int)(MK / K);
    const int N = (int)(NK / K);

    const size_t needI = (size_t)MK + (size_t)NK + 4ull * M + 64ull * M +
                         64ull * N + 4ull * N;
    bool i8ok = (G == 128) && (K == 4096) && (M % 256 == 0) && (N % 256 == 0) &&
                (ws_size >= needI);
    if (i8ok) {
        if (hipFuncSetAttribute((const void*)gemm_i8,
                                hipFuncAttributeMaxDynamicSharedMemorySize,
                                131072) != hipSuccess)
            i8ok = false;
        (void)hipGetLastError();
    }
    if (i8ok) {
        signed char* Xq = (signed char*)d_ws;
        signed char* Wq = Xq + MK;
        float*       SX = (float*)(Wq + NK);
        __bf16*      XS = (__bf16*)((char*)SX + 4ull * M);
        __bf16*      ZT = (__bf16*)((char*)XS + 64ull * M);
        float*       SW = (float*)((char*)ZT + 64ull * N);

        const int nwaves = N + M;
        const int nblk   = (nwaves + 3) / 4;          // 4 waves per 256-thr block
        prep_all<<<nblk, 256, 0, stream>>>(X, Q, S, Z, Xq, Wq, SX, SW, XS, ZT,
                                           M, N, K);
        gemm_i8<<<(M / 256) * (N / 256), 512, 131072, stream>>>(
            Xq, Wq, SW, SX, XS, ZT, Y, M, N, K);
        if (hipGetLastError() == hipSuccess) return;
    }

    const size_t need = ((size_t)M * K + (size_t)N * K) * sizeof(__bf16);
    if (ws_size >= need) {
        __bf16* Xbf = (__bf16*)d_ws;
        __bf16* Wbf = Xbf + (size_t)M * K;
        prep_ab<<<2048, 256, 0, stream>>>(X, Q, S, Z, Xbf, Wbf,
                                          (long)M * K / 8, N, K, G);
        gemm_bf16_bt<<<(M / TM) * (N / TN), 256, 0, stream>>>(Xbf, Wbf, Y, M, N, K);
    } else {
        qlin_fused<<<(M / TM) * (N / TN), 256, 0, stream>>>(X, Q, S, Z, Y, M, N, K, G);
    }
}